// Round 11
// baseline (2810.169 us; speedup 1.0000x reference)
//
#include <hip/hip_runtime.h>

// Encoder: 3x [conv1d(K=5,pad2)+BN+ReLU] -> biLSTM(H=256) zoneout(0.1).  MFMA convs/gates; VALU recurrence.
// r10 lstm: per-WAVE k-split + v_readlane h-broadcast (1 ds_read_b32/wave/step instead of 16 b128/thread),
//           weights 100 pairs in VGPR + 28 in LDS (7 uint4 slots, ds_read_b128), float2 pbuf combine.
// ws:    A f16 [32][1000][512] @0 (32,768,000) | G f16 [2][100][32][1024] @32,768,000 (13,107,200)
//        | state @45,875,200 (131,072) | W16 @46,006,272 (1,048,576) | Wg f16 [2][1024][512] @47,054,848 (2,097,152)
//        -> 49,152,000 B
// d_out: Bd (conv1 out) @0 | Wp0 @36,000,000 | Wp1 @36,409,600 | Wp2 @41,652,480 | Xt0 @46,895,360

#define T_LEN 1000
#define NBATCH 32
#define CCH 512
#define HDIM 256
#define GDIM 1024
#define TC 100
#define WREG_N 100      // reg pair-slots per thread (rowA 64 + rowB 36)
#define WLDS_S 7        // LDS uint4 slots per thread (rowB pairs 36..63)

typedef _Float16 h16;
typedef _Float16 h16x2 __attribute__((ext_vector_type(2)));
typedef _Float16 f16x8 __attribute__((ext_vector_type(8)));
typedef float    f32x4 __attribute__((ext_vector_type(4)));

__device__ __forceinline__ float fixup(float v, float alt){
    union { float f; unsigned u; } c; c.f = v;
    return ((c.u & 0x7f800000u) == 0x7f800000u) ? alt : v;
}
__device__ __forceinline__ float clamp_s(float v, float lo, float hi){
    return fminf(fmaxf(v, lo), hi);
}
__device__ __forceinline__ float sigm(float x){
    const float xc = clamp_s(x, -30.f, 30.f);
    return 1.0f / (1.0f + __expf(-xc));
}
__device__ __forceinline__ float tanh_safe(float x){
    const float ax = fminf(fabsf(x), 30.0f);
    const float t  = __expf(-2.0f * ax);
    const float r  = (1.0f - t) / (1.0f + t);
    return copysignf(r, x);
}
__device__ __forceinline__ float mac2(unsigned hp, unsigned wp, float acc){
    union Cv { unsigned u; h16 h[2]; };
    Cv a, b; a.u = hp; b.u = wp;
    acc += (float)a.h[0] * (float)b.h[0];
    acc += (float)a.h[1] * (float)b.h[1];
    return acc;
}
__device__ __forceinline__ float dot2(unsigned hp, unsigned wp, float acc){
#if defined(__has_builtin) && __has_builtin(__builtin_amdgcn_fdot2)
    union Cv { unsigned u; h16x2 v; };
    Cv a, b; a.u = hp; b.u = wp;
    return __builtin_amdgcn_fdot2(a.v, b.v, acc, false);
#else
    return mac2(hp, wp, acc);
#endif
}
__device__ __forceinline__ unsigned packh2(float x, float y){
    union Cv { unsigned u; h16 h[2]; };
    Cv c; c.h[0] = (h16)x; c.h[1] = (h16)y;
    return c.u;
}

// ---------------- packs ----------------
// cw f32 [512][cin][5] -> Wp f16 [5][512][cin]
__global__ __launch_bounds__(256)
void pack_convw_kernel(const float* __restrict__ cw, h16* __restrict__ Wp, int cin)
{
    const int n = blockIdx.x*256 + threadIdx.x;
    if (n >= 5*512*cin) return;
    const int k   = n / (512*cin);
    const int rem = n - k*512*cin;
    const int co  = rem / cin;
    const int ci  = rem - co*cin;
    Wp[n] = (h16)cw[((size_t)co*cin + ci)*5 + k];
}

// wih f32 [1024][512] x2 -> Wg f16 [2][1024][512]
__global__ __launch_bounds__(256)
void pack_wih_kernel(const float* __restrict__ wf, const float* __restrict__ wb, h16* __restrict__ Wg)
{
    const int n = blockIdx.x*256 + threadIdx.x;
    const float* src = (n < 1024*512) ? wf : wb;
    Wg[n] = (h16)src[n & (1024*512 - 1)];
}

// whh f32 -> wave-k-split pack for lstm r10.
// Thread t: half=(t>>6)&1, q=t>>7, l=t&63; rows rA=q*128+2l, rB=rA+1; k-pairs P in [half*64, half*64+64).
//   reg  part [2][100][1024] u32 : slot<64  -> (rA, half*64+slot) ; 64<=slot<100 -> (rB, half*64+slot-64)
//   lds  part [2][7][1024] uint4 at u32 offset 204800 : s=slot-100 in 0..27 -> (rB, half*64+36+s),
//        addr_u32 = 204800 + dir*28672 + (s>>2)*4096 + t*4 + (s&3)
__global__ __launch_bounds__(256)
void whh_prep_kernel(const float* __restrict__ whh_f, const float* __restrict__ whh_b,
                     unsigned* __restrict__ W16)
{
    const int n = blockIdx.x * 256 + threadIdx.x;   // 2*128*1024
    if (n >= 2*128*1024) return;
    const int dir  = n >> 17;
    const int slot = (n >> 10) & 127;
    const int t    = n & 1023;
    const float* whh = dir ? whh_b : whh_f;
    const int half = (t >> 6) & 1;
    const int q    = t >> 7;
    const int l    = t & 63;
    const int rA   = q*128 + 2*l;
    int row, P;
    size_t addr;
    if (slot < 64) {
        row = rA; P = half*64 + slot;
        addr = (size_t)dir*WREG_N*1024 + (size_t)slot*1024 + t;
    } else if (slot < 100) {
        row = rA + 1; P = half*64 + (slot - 64);
        addr = (size_t)dir*WREG_N*1024 + (size_t)slot*1024 + t;
    } else {
        const int s = slot - 100;                    // 0..27
        row = rA + 1; P = half*64 + 36 + s;
        addr = (size_t)204800 + (size_t)dir*28672 + (size_t)(s >> 2)*4096 + (size_t)t*4 + (s & 3);
    }
    W16[addr] = packh2(whh[(size_t)row*HDIM + 2*P], whh[(size_t)row*HDIM + 2*P + 1]);
}

// x f32 [32][80][1000] -> Xt0 f16 [32][1000][80]
__global__ __launch_bounds__(256)
void x0_transpose_kernel(const float* __restrict__ x, h16* __restrict__ Xt0)
{
    const int b = blockIdx.y;
    const int t = blockIdx.x*256 + threadIdx.x;
    if (t >= T_LEN) return;
    h16 v[80];
    #pragma unroll
    for (int c = 0; c < 80; ++c) v[c] = (h16)x[((size_t)b*80 + c)*T_LEN + t];
    #pragma unroll
    for (int g = 0; g < 10; ++g)
        *(f16x8*)(Xt0 + ((size_t)b*T_LEN + t)*80 + g*8) = *(const f16x8*)(v + g*8);
}

// ---------------- conv (implicit GEMM, MFMA 16x16x32 f16) ----------------
__global__ __attribute__((amdgpu_flat_work_group_size(512,512), amdgpu_waves_per_eu(4,4)))
void conv_mfma_kernel(const h16* __restrict__ Xt, const h16* __restrict__ Wp,
                      h16* __restrict__ outp,
                      const float* __restrict__ cb, const float* __restrict__ bg,
                      const float* __restrict__ bb, const float* __restrict__ bm,
                      const float* __restrict__ bv, int cin)
{
    const int t0   = blockIdx.x * 128;
    const int co0  = blockIdx.y * 128;
    const int b    = blockIdx.z;
    const int tid  = threadIdx.x;
    const int lane = tid & 63;
    const int w    = tid >> 6;
    const int wm   = w >> 2;
    const int wn   = w & 3;
    const int lr   = lane & 15;
    const int lg   = lane >> 4;

    __shared__ __align__(16) h16 Xs[132*40];
    __shared__ __align__(16) h16 Ws[5*128*40];

    f32x4 acc[4][2];
    #pragma unroll
    for (int m = 0; m < 4; ++m)
        #pragma unroll
        for (int n = 0; n < 2; ++n)
            #pragma unroll
            for (int r = 0; r < 4; ++r) acc[m][n][r] = 0.f;

    const int ksteps = (cin + 31) >> 5;
    for (int cs = 0; cs < ksteps; ++cs) {
        const int c0 = cs << 5;
        for (int id = tid; id < 132*4; id += 512) {
            const int row = id >> 2, g = id & 3;
            const int t = t0 + row - 2;
            f16x8 v;
            #pragma unroll
            for (int j = 0; j < 8; ++j) v[j] = (h16)0.f;
            if (t >= 0 && t < T_LEN) {
                const int c = c0 + g*8;
                if (c + 8 <= cin) {
                    v = *(const f16x8*)(Xt + ((size_t)b*T_LEN + t)*cin + c);
                } else if (c < cin) {
                    #pragma unroll
                    for (int j = 0; j < 8; ++j) if (c + j < cin) v[j] = Xt[((size_t)b*T_LEN + t)*cin + c + j];
                }
            }
            *(f16x8*)(Xs + row*40 + g*8) = v;
        }
        for (int id = tid; id < 5*128*4; id += 512) {
            const int k  = id >> 9;
            const int co = (id >> 2) & 127;
            const int g  = id & 3;
            const int c  = c0 + g*8;
            f16x8 v;
            #pragma unroll
            for (int j = 0; j < 8; ++j) v[j] = (h16)0.f;
            if (c + 8 <= cin) {
                v = *(const f16x8*)(Wp + ((size_t)k*512 + co0 + co)*cin + c);
            } else if (c < cin) {
                #pragma unroll
                for (int j = 0; j < 8; ++j) if (c + j < cin) v[j] = Wp[((size_t)k*512 + co0 + co)*cin + c + j];
            }
            *(f16x8*)(Ws + (k*128 + co)*40 + g*8) = v;
        }
        __syncthreads();

        #pragma unroll
        for (int k = 0; k < 5; ++k) {
            const f16x8 b0 = *(const f16x8*)(Ws + (k*128 + wn*32 +      lr)*40 + lg*8);
            const f16x8 b1 = *(const f16x8*)(Ws + (k*128 + wn*32 + 16 + lr)*40 + lg*8);
            #pragma unroll
            for (int m = 0; m < 4; ++m) {
                const f16x8 a = *(const f16x8*)(Xs + (wm*64 + m*16 + lr + k)*40 + lg*8);
                acc[m][0] = __builtin_amdgcn_mfma_f32_16x16x32_f16(a, b0, acc[m][0], 0, 0, 0);
                acc[m][1] = __builtin_amdgcn_mfma_f32_16x16x32_f16(a, b1, acc[m][1], 0, 0, 0);
            }
        }
        __syncthreads();
    }

    #pragma unroll
    for (int nf = 0; nf < 2; ++nf) {
        const int co = co0 + wn*32 + nf*16 + lr;
        const float s  = bg[co] * rsqrtf(fmaxf(bv[co] + 1e-5f, 1e-8f));
        const float sh = (cb[co] - bm[co]) * s + bb[co];
        #pragma unroll
        for (int m = 0; m < 4; ++m) {
            #pragma unroll
            for (int r = 0; r < 4; ++r) {
                const int t = t0 + wm*64 + m*16 + lg*4 + r;
                if (t < T_LEN) {
                    const float y = fixup(clamp_s(fmaxf(acc[m][nf][r]*s + sh, 0.f), 0.f, 60000.f), 0.f);
                    outp[((size_t)b*T_LEN + t)*CCH + co] = (h16)y;
                }
            }
        }
    }
}

// ---------------- gates GEMM (MFMA), one time-chunk, both dirs ----------------
__global__ __attribute__((amdgpu_flat_work_group_size(256,256), amdgpu_waves_per_eu(4,4)))
void gates_mfma_kernel(const h16* __restrict__ Xt,
                       const h16* __restrict__ Wg,
                       const float* __restrict__ bih_f, const float* __restrict__ bhh_f,
                       const float* __restrict__ bih_b, const float* __restrict__ bhh_b,
                       h16* __restrict__ G, int t0f, int t0b)
{
    const int tt   = blockIdx.x;
    const int r0   = blockIdx.y * 128;
    const int b    = blockIdx.z & 31;
    const int dir  = blockIdx.z >> 5;
    const int t0c  = dir ? t0b : t0f;
    const int tid  = threadIdx.x;
    const int lane = tid & 63;
    const int w    = tid >> 6;
    const int lr   = lane & 15;
    const int lg   = lane >> 4;
    const float* bi = dir ? bih_b : bih_f;
    const float* bh = dir ? bhh_b : bhh_f;
    const h16* Wd = Wg + (size_t)dir*1024*512;

    __shared__ __align__(16) h16 Xs[64*40];
    __shared__ __align__(16) h16 Ws[128*40];

    f32x4 acc[4][2];
    #pragma unroll
    for (int m = 0; m < 4; ++m)
        #pragma unroll
        for (int n = 0; n < 2; ++n)
            #pragma unroll
            for (int r = 0; r < 4; ++r) acc[m][n][r] = 0.f;

    for (int cs = 0; cs < 16; ++cs) {
        const int c0 = cs << 5;
        for (int id = tid; id < 64*4; id += 256) {
            const int row = id >> 2, g = id & 3;
            int t = t0c + tt*64 + row; if (t >= T_LEN) t = T_LEN - 1;
            *(f16x8*)(Xs + row*40 + g*8) = *(const f16x8*)(Xt + ((size_t)b*T_LEN + t)*CCH + c0 + g*8);
        }
        for (int id = tid; id < 128*4; id += 256) {
            const int row = id >> 2, g = id & 3;
            *(f16x8*)(Ws + row*40 + g*8) = *(const f16x8*)(Wd + (size_t)(r0 + row)*CCH + c0 + g*8);
        }
        __syncthreads();

        const f16x8 b0 = *(const f16x8*)(Ws + (w*32 +      lr)*40 + lg*8);
        const f16x8 b1 = *(const f16x8*)(Ws + (w*32 + 16 + lr)*40 + lg*8);
        #pragma unroll
        for (int m = 0; m < 4; ++m) {
            const f16x8 a = *(const f16x8*)(Xs + (m*16 + lr)*40 + lg*8);
            acc[m][0] = __builtin_amdgcn_mfma_f32_16x16x32_f16(a, b0, acc[m][0], 0, 0, 0);
            acc[m][1] = __builtin_amdgcn_mfma_f32_16x16x32_f16(a, b1, acc[m][1], 0, 0, 0);
        }
        __syncthreads();
    }

    #pragma unroll
    for (int nf = 0; nf < 2; ++nf) {
        const int row = r0 + w*32 + nf*16 + lr;
        const float bias = bi[row] + bh[row];
        #pragma unroll
        for (int m = 0; m < 4; ++m) {
            #pragma unroll
            for (int r = 0; r < 4; ++r) {
                const int tl = tt*64 + m*16 + lg*4 + r;
                if (tl < TC)
                    G[(((size_t)dir*TC + tl)*NBATCH + b)*GDIM + row]
                        = (h16)fixup(clamp_s(acc[m][nf][r] + bias, -60000.f, 60000.f), 0.f);
            }
        }
    }
}

// ---------------- persistent biLSTM recurrence, wave-k-split + readlane broadcast ----------------
// Thread t: half=(t>>6)&1 (wave parity = k-half), q=t>>7, l=t&63; rows rA=q*128+2l, rB=rA+1.
// Per step: 1 ds_read_b32 loads h k-half lane-distributed; v_readlane broadcasts pair j (VALU, not LDS).
// Partials (rA,rB) written as float2 to pbuf[half][row]; tid<256 combines + elementwise.
__global__ __attribute__((amdgpu_flat_work_group_size(1024, 1024), amdgpu_waves_per_eu(4, 4)))
void lstm_chunk_kernel(const h16* __restrict__ G,
                       const unsigned* __restrict__ W16,
                       float* __restrict__ state,
                       float* __restrict__ out,
                       int t0f, int t0b, int first)
{
    const int tid  = threadIdx.x;
    const int lane = tid & 63;
    const int half = (tid >> 6) & 1;
    const int q    = tid >> 7;
    const int dir  = blockIdx.x >> 5;
    const int b    = blockIdx.x & 31;
    const int t0   = dir ? t0b : t0f;
    float* st = state + ((size_t)(dir*NBATCH + b))*2*HDIM;
    const unsigned* Wreg  = W16 + (size_t)dir*WREG_N*1024;
    const uint4*    Wlds4 = (const uint4*)(W16 + 204800 + (size_t)dir*28672);

    __shared__ __align__(16) uint4 lw4[WLDS_S*1024];   // 114,688 B
    __shared__ __align__(16) unsigned hs[HDIM/2];      // h as 128 f16-pairs
    __shared__ float pbuf[2*GDIM];                     // [half][row] partial sums, 8 KB

    unsigned wreg[WREG_N];
    #pragma unroll
    for (int p = 0; p < WREG_N; ++p)
        wreg[p] = Wreg[p*1024 + tid];                  // lane-coalesced

    #pragma unroll
    for (int s = 0; s < WLDS_S; ++s)
        lw4[s*1024 + tid] = Wlds4[s*1024 + tid];       // coalesced 16B/thread

    float hst = 0.0f, cst = 0.0f;
    if (tid < HDIM && !first) { hst = st[tid]; cst = st[HDIM + tid]; }
    if (tid < HDIM/2) {
        const float h0 = first ? 0.0f : st[2*tid];
        const float h1 = first ? 0.0f : st[2*tid + 1];
        hs[tid] = packh2(h0, h1);
    }
    __syncthreads();

    float2* pbuf2 = (float2*)pbuf;

    for (int i = 0; i < TC; ++i) {
        const int sl = dir ? (TC - 1 - i) : i;
        const int t  = t0 + sl;
        const h16* gp = G + (((size_t)dir*TC + sl)*NBATCH + b)*GDIM;
        float g0 = 0.f, g1 = 0.f, g2 = 0.f, g3 = 0.f;
        if (tid < HDIM) {                               // issue early; hidden under dot phase
            g0 = (float)gp[tid];
            g1 = (float)gp[HDIM + tid];
            g2 = (float)gp[2*HDIM + tid];
            g3 = (float)gp[3*HDIM + tid];
        }

        const unsigned wv = hs[(half << 6) | lane];     // 1 ds_read_b32: lane l holds pair (half*64+l)

        float aA0 = 0.f, aA1 = 0.f, aB0 = 0.f, aB1 = 0.f;
        uint4 lwv;
        #pragma unroll
        for (int j = 0; j < 64; ++j) {
            const unsigned s = (unsigned)__builtin_amdgcn_readlane((int)wv, j);  // VALU broadcast
            if ((j & 1) == 0) aA0 = dot2(s, wreg[j], aA0);
            else              aA1 = dot2(s, wreg[j], aA1);
            if (j < 36) {
                if ((j & 1) == 0) aB0 = dot2(s, wreg[64 + j], aB0);
                else              aB1 = dot2(s, wreg[64 + j], aB1);
            } else {
                const int jj = j - 36;
                if ((jj & 3) == 0) lwv = lw4[(jj >> 2)*1024 + tid];              // ds_read_b128
                const unsigned wp = ((const unsigned*)&lwv)[jj & 3];             // const idx after unroll
                if ((j & 1) == 0) aB0 = dot2(s, wp, aB0);
                else              aB1 = dot2(s, wp, aB1);
            }
        }
        // partials for rows rA=q*128+2l (x) and rB=rA+1 (y)
        pbuf2[(half << 9) | (q << 6) | lane] = make_float2(aA0 + aA1, aB0 + aB1);
        __syncthreads();

        if (tid < HDIM) {
            const float gi = g0 + pbuf[tid]            + pbuf[GDIM + tid];
            const float gf = g1 + pbuf[HDIM + tid]     + pbuf[GDIM + HDIM + tid];
            const float gg = g2 + pbuf[2*HDIM + tid]   + pbuf[GDIM + 2*HDIM + tid];
            const float go = g3 + pbuf[3*HDIM + tid]   + pbuf[GDIM + 3*HDIM + tid];
            const float c2 = sigm(gf)*cst + sigm(gi)*tanh_safe(gg);
            const float h2 = sigm(go)*tanh_safe(c2);
            hst = 0.1f*hst + 0.9f*h2;                   // zoneout (output is post-zoneout h)
            cst = 0.1f*cst + 0.9f*c2;
            out[((size_t)b*T_LEN + t)*(2*HDIM) + dir*HDIM + tid] = fixup(hst, 50.0f);
            const float hn = __shfl_xor(hst, 1);
            if ((tid & 1) == 0) hs[tid >> 1] = packh2(hst, hn);
        }
        __syncthreads();
    }

    if (tid < HDIM) { st[tid] = hst; st[HDIM + tid] = cst; }
}

extern "C" void kernel_launch(void* const* d_in, const int* in_sizes, int n_in,
                              void* d_out, int out_size, void* d_ws, size_t ws_size,
                              hipStream_t stream)
{
    (void)in_sizes; (void)n_in; (void)out_size;
    if (ws_size < 49152000) return;

    const float* x     = (const float*)d_in[0];
    const float* cw0   = (const float*)d_in[1];
    const float* cb0   = (const float*)d_in[2];
    const float* bg0   = (const float*)d_in[3];
    const float* bb0   = (const float*)d_in[4];
    const float* bm0   = (const float*)d_in[5];
    const float* bv0   = (const float*)d_in[6];
    const float* cw1   = (const float*)d_in[7];
    const float* cb1   = (const float*)d_in[8];
    const float* bg1   = (const float*)d_in[9];
    const float* bb1   = (const float*)d_in[10];
    const float* bm1   = (const float*)d_in[11];
    const float* bv1   = (const float*)d_in[12];
    const float* cw2   = (const float*)d_in[13];
    const float* cb2   = (const float*)d_in[14];
    const float* bg2   = (const float*)d_in[15];
    const float* bb2   = (const float*)d_in[16];
    const float* bm2   = (const float*)d_in[17];
    const float* bv2   = (const float*)d_in[18];
    const float* wih_f = (const float*)d_in[19];
    const float* whh_f = (const float*)d_in[20];
    const float* bih_f = (const float*)d_in[21];
    const float* bhh_f = (const float*)d_in[22];
    const float* wih_b = (const float*)d_in[23];
    const float* whh_b = (const float*)d_in[24];
    const float* bih_b = (const float*)d_in[25];
    const float* bhh_b = (const float*)d_in[26];

    char* ws = (char*)d_ws;
    char* od = (char*)d_out;
    h16*      A   = (h16*)(ws);
    h16*      G   = (h16*)(ws + 32768000);
    float*    st  = (float*)(ws + 45875200);
    unsigned* W16 = (unsigned*)(ws + 46006272);
    h16*      Wg  = (h16*)(ws + 47054848);
    h16*      Bd  = (h16*)(od);
    h16*      Wp0 = (h16*)(od + 36000000);
    h16*      Wp1 = (h16*)(od + 36409600);
    h16*      Wp2 = (h16*)(od + 41652480);
    h16*      Xt0 = (h16*)(od + 46895360);
    float*    out = (float*)d_out;

    // packs
    pack_convw_kernel<<<dim3((5*512*80  + 255)/256), 256, 0, stream>>>(cw0, Wp0, 80);
    pack_convw_kernel<<<dim3((5*512*512 + 255)/256), 256, 0, stream>>>(cw1, Wp1, 512);
    pack_convw_kernel<<<dim3((5*512*512 + 255)/256), 256, 0, stream>>>(cw2, Wp2, 512);
    pack_wih_kernel<<<dim3(2*1024*512/256), 256, 0, stream>>>(wih_f, wih_b, Wg);
    whh_prep_kernel<<<dim3(1024), 256, 0, stream>>>(whh_f, whh_b, W16);
    x0_transpose_kernel<<<dim3(4, 32), 256, 0, stream>>>(x, Xt0);

    // convs (implicit-GEMM MFMA)
    const dim3 cgrid(8, 4, 32);
    conv_mfma_kernel<<<cgrid, 512, 0, stream>>>(Xt0, Wp0, A,  cb0, bg0, bb0, bm0, bv0, 80);
    conv_mfma_kernel<<<cgrid, 512, 0, stream>>>(A,   Wp1, Bd, cb1, bg1, bb1, bm1, bv1, 512);
    conv_mfma_kernel<<<cgrid, 512, 0, stream>>>(Bd,  Wp2, A,  cb2, bg2, bb2, bm2, bv2, 512);

    for (int c = 0; c < T_LEN / TC; ++c) {
        const int t0f = c * TC;
        const int t0b = (T_LEN - TC) - c * TC;
        gates_mfma_kernel<<<dim3(2, 8, 64), 256, 0, stream>>>(A, Wg, bih_f, bhh_f, bih_b, bhh_b, G, t0f, t0b);
        lstm_chunk_kernel<<<dim3(64), 1024, 0, stream>>>(G, W16, st, out, t0f, t0b, c == 0);
    }
}

// Round 12
// 2783.955 us; speedup vs baseline: 1.0094x; 1.0094x over previous
//
#include <hip/hip_runtime.h>

// Encoder: 3x [conv1d(K=5,pad2)+BN+ReLU] -> biLSTM(H=256) zoneout(0.1).  MFMA convs/gates; VALU recurrence.
// r12 lstm: waves_per_eu(1,4) (remove VGPR cap) + out-store deferred one step (drain hidden under dot phase).
// ws:    A f16 [32][1000][512] @0 (32,768,000) | G f16 [2][100][32][1024] @32,768,000 (13,107,200)
//        | state @45,875,200 (131,072) | W16 @46,006,272 (1,048,576) | Wg f16 [2][1024][512] @47,054,848 (2,097,152)
//        -> 49,152,000 B
// d_out: Bd (conv1 out) @0 | Wp0 @36,000,000 | Wp1 @36,409,600 | Wp2 @41,652,480 | Xt0 @46,895,360

#define T_LEN 1000
#define NBATCH 32
#define CCH 512
#define HDIM 256
#define GDIM 1024
#define TC 100
#define WREG_N 100      // reg pair-slots per thread (rowA 64 + rowB 36)
#define WLDS_S 7        // LDS uint4 slots per thread (rowB pairs 36..63)

typedef _Float16 h16;
typedef _Float16 h16x2 __attribute__((ext_vector_type(2)));
typedef _Float16 f16x8 __attribute__((ext_vector_type(8)));
typedef float    f32x4 __attribute__((ext_vector_type(4)));

__device__ __forceinline__ float fixup(float v, float alt){
    union { float f; unsigned u; } c; c.f = v;
    return ((c.u & 0x7f800000u) == 0x7f800000u) ? alt : v;
}
__device__ __forceinline__ float clamp_s(float v, float lo, float hi){
    return fminf(fmaxf(v, lo), hi);
}
__device__ __forceinline__ float sigm(float x){
    const float xc = clamp_s(x, -30.f, 30.f);
    return 1.0f / (1.0f + __expf(-xc));
}
__device__ __forceinline__ float tanh_safe(float x){
    const float ax = fminf(fabsf(x), 30.0f);
    const float t  = __expf(-2.0f * ax);
    const float r  = (1.0f - t) / (1.0f + t);
    return copysignf(r, x);
}
__device__ __forceinline__ float mac2(unsigned hp, unsigned wp, float acc){
    union Cv { unsigned u; h16 h[2]; };
    Cv a, b; a.u = hp; b.u = wp;
    acc += (float)a.h[0] * (float)b.h[0];
    acc += (float)a.h[1] * (float)b.h[1];
    return acc;
}
__device__ __forceinline__ float dot2(unsigned hp, unsigned wp, float acc){
#if defined(__has_builtin) && __has_builtin(__builtin_amdgcn_fdot2)
    union Cv { unsigned u; h16x2 v; };
    Cv a, b; a.u = hp; b.u = wp;
    return __builtin_amdgcn_fdot2(a.v, b.v, acc, false);
#else
    return mac2(hp, wp, acc);
#endif
}
__device__ __forceinline__ unsigned packh2(float x, float y){
    union Cv { unsigned u; h16 h[2]; };
    Cv c; c.h[0] = (h16)x; c.h[1] = (h16)y;
    return c.u;
}

// ---------------- packs ----------------
// cw f32 [512][cin][5] -> Wp f16 [5][512][cin]
__global__ __launch_bounds__(256)
void pack_convw_kernel(const float* __restrict__ cw, h16* __restrict__ Wp, int cin)
{
    const int n = blockIdx.x*256 + threadIdx.x;
    if (n >= 5*512*cin) return;
    const int k   = n / (512*cin);
    const int rem = n - k*512*cin;
    const int co  = rem / cin;
    const int ci  = rem - co*cin;
    Wp[n] = (h16)cw[((size_t)co*cin + ci)*5 + k];
}

// wih f32 [1024][512] x2 -> Wg f16 [2][1024][512]
__global__ __launch_bounds__(256)
void pack_wih_kernel(const float* __restrict__ wf, const float* __restrict__ wb, h16* __restrict__ Wg)
{
    const int n = blockIdx.x*256 + threadIdx.x;
    const float* src = (n < 1024*512) ? wf : wb;
    Wg[n] = (h16)src[n & (1024*512 - 1)];
}

// whh f32 -> wave-k-split pack (unchanged from r10/r11).
// Thread t: half=(t>>6)&1, q=t>>7, l=t&63; rows rA=q*128+2l, rB=rA+1; k-pairs P in [half*64, half*64+64).
__global__ __launch_bounds__(256)
void whh_prep_kernel(const float* __restrict__ whh_f, const float* __restrict__ whh_b,
                     unsigned* __restrict__ W16)
{
    const int n = blockIdx.x * 256 + threadIdx.x;   // 2*128*1024
    if (n >= 2*128*1024) return;
    const int dir  = n >> 17;
    const int slot = (n >> 10) & 127;
    const int t    = n & 1023;
    const float* whh = dir ? whh_b : whh_f;
    const int half = (t >> 6) & 1;
    const int q    = t >> 7;
    const int l    = t & 63;
    const int rA   = q*128 + 2*l;
    int row, P;
    size_t addr;
    if (slot < 64) {
        row = rA; P = half*64 + slot;
        addr = (size_t)dir*WREG_N*1024 + (size_t)slot*1024 + t;
    } else if (slot < 100) {
        row = rA + 1; P = half*64 + (slot - 64);
        addr = (size_t)dir*WREG_N*1024 + (size_t)slot*1024 + t;
    } else {
        const int s = slot - 100;                    // 0..27
        row = rA + 1; P = half*64 + 36 + s;
        addr = (size_t)204800 + (size_t)dir*28672 + (size_t)(s >> 2)*4096 + (size_t)t*4 + (s & 3);
    }
    W16[addr] = packh2(whh[(size_t)row*HDIM + 2*P], whh[(size_t)row*HDIM + 2*P + 1]);
}

// x f32 [32][80][1000] -> Xt0 f16 [32][1000][80]
__global__ __launch_bounds__(256)
void x0_transpose_kernel(const float* __restrict__ x, h16* __restrict__ Xt0)
{
    const int b = blockIdx.y;
    const int t = blockIdx.x*256 + threadIdx.x;
    if (t >= T_LEN) return;
    h16 v[80];
    #pragma unroll
    for (int c = 0; c < 80; ++c) v[c] = (h16)x[((size_t)b*80 + c)*T_LEN + t];
    #pragma unroll
    for (int g = 0; g < 10; ++g)
        *(f16x8*)(Xt0 + ((size_t)b*T_LEN + t)*80 + g*8) = *(const f16x8*)(v + g*8);
}

// ---------------- conv (implicit GEMM, MFMA 16x16x32 f16) ----------------
__global__ __attribute__((amdgpu_flat_work_group_size(512,512), amdgpu_waves_per_eu(4,4)))
void conv_mfma_kernel(const h16* __restrict__ Xt, const h16* __restrict__ Wp,
                      h16* __restrict__ outp,
                      const float* __restrict__ cb, const float* __restrict__ bg,
                      const float* __restrict__ bb, const float* __restrict__ bm,
                      const float* __restrict__ bv, int cin)
{
    const int t0   = blockIdx.x * 128;
    const int co0  = blockIdx.y * 128;
    const int b    = blockIdx.z;
    const int tid  = threadIdx.x;
    const int lane = tid & 63;
    const int w    = tid >> 6;
    const int wm   = w >> 2;
    const int wn   = w & 3;
    const int lr   = lane & 15;
    const int lg   = lane >> 4;

    __shared__ __align__(16) h16 Xs[132*40];
    __shared__ __align__(16) h16 Ws[5*128*40];

    f32x4 acc[4][2];
    #pragma unroll
    for (int m = 0; m < 4; ++m)
        #pragma unroll
        for (int n = 0; n < 2; ++n)
            #pragma unroll
            for (int r = 0; r < 4; ++r) acc[m][n][r] = 0.f;

    const int ksteps = (cin + 31) >> 5;
    for (int cs = 0; cs < ksteps; ++cs) {
        const int c0 = cs << 5;
        for (int id = tid; id < 132*4; id += 512) {
            const int row = id >> 2, g = id & 3;
            const int t = t0 + row - 2;
            f16x8 v;
            #pragma unroll
            for (int j = 0; j < 8; ++j) v[j] = (h16)0.f;
            if (t >= 0 && t < T_LEN) {
                const int c = c0 + g*8;
                if (c + 8 <= cin) {
                    v = *(const f16x8*)(Xt + ((size_t)b*T_LEN + t)*cin + c);
                } else if (c < cin) {
                    #pragma unroll
                    for (int j = 0; j < 8; ++j) if (c + j < cin) v[j] = Xt[((size_t)b*T_LEN + t)*cin + c + j];
                }
            }
            *(f16x8*)(Xs + row*40 + g*8) = v;
        }
        for (int id = tid; id < 5*128*4; id += 512) {
            const int k  = id >> 9;
            const int co = (id >> 2) & 127;
            const int g  = id & 3;
            const int c  = c0 + g*8;
            f16x8 v;
            #pragma unroll
            for (int j = 0; j < 8; ++j) v[j] = (h16)0.f;
            if (c + 8 <= cin) {
                v = *(const f16x8*)(Wp + ((size_t)k*512 + co0 + co)*cin + c);
            } else if (c < cin) {
                #pragma unroll
                for (int j = 0; j < 8; ++j) if (c + j < cin) v[j] = Wp[((size_t)k*512 + co0 + co)*cin + c + j];
            }
            *(f16x8*)(Ws + (k*128 + co)*40 + g*8) = v;
        }
        __syncthreads();

        #pragma unroll
        for (int k = 0; k < 5; ++k) {
            const f16x8 b0 = *(const f16x8*)(Ws + (k*128 + wn*32 +      lr)*40 + lg*8);
            const f16x8 b1 = *(const f16x8*)(Ws + (k*128 + wn*32 + 16 + lr)*40 + lg*8);
            #pragma unroll
            for (int m = 0; m < 4; ++m) {
                const f16x8 a = *(const f16x8*)(Xs + (wm*64 + m*16 + lr + k)*40 + lg*8);
                acc[m][0] = __builtin_amdgcn_mfma_f32_16x16x32_f16(a, b0, acc[m][0], 0, 0, 0);
                acc[m][1] = __builtin_amdgcn_mfma_f32_16x16x32_f16(a, b1, acc[m][1], 0, 0, 0);
            }
        }
        __syncthreads();
    }

    #pragma unroll
    for (int nf = 0; nf < 2; ++nf) {
        const int co = co0 + wn*32 + nf*16 + lr;
        const float s  = bg[co] * rsqrtf(fmaxf(bv[co] + 1e-5f, 1e-8f));
        const float sh = (cb[co] - bm[co]) * s + bb[co];
        #pragma unroll
        for (int m = 0; m < 4; ++m) {
            #pragma unroll
            for (int r = 0; r < 4; ++r) {
                const int t = t0 + wm*64 + m*16 + lg*4 + r;
                if (t < T_LEN) {
                    const float y = fixup(clamp_s(fmaxf(acc[m][nf][r]*s + sh, 0.f), 0.f, 60000.f), 0.f);
                    outp[((size_t)b*T_LEN + t)*CCH + co] = (h16)y;
                }
            }
        }
    }
}

// ---------------- gates GEMM (MFMA), one time-chunk, both dirs ----------------
__global__ __attribute__((amdgpu_flat_work_group_size(256,256), amdgpu_waves_per_eu(4,4)))
void gates_mfma_kernel(const h16* __restrict__ Xt,
                       const h16* __restrict__ Wg,
                       const float* __restrict__ bih_f, const float* __restrict__ bhh_f,
                       const float* __restrict__ bih_b, const float* __restrict__ bhh_b,
                       h16* __restrict__ G, int t0f, int t0b)
{
    const int tt   = blockIdx.x;
    const int r0   = blockIdx.y * 128;
    const int b    = blockIdx.z & 31;
    const int dir  = blockIdx.z >> 5;
    const int t0c  = dir ? t0b : t0f;
    const int tid  = threadIdx.x;
    const int lane = tid & 63;
    const int w    = tid >> 6;
    const int lr   = lane & 15;
    const int lg   = lane >> 4;
    const float* bi = dir ? bih_b : bih_f;
    const float* bh = dir ? bhh_b : bhh_f;
    const h16* Wd = Wg + (size_t)dir*1024*512;

    __shared__ __align__(16) h16 Xs[64*40];
    __shared__ __align__(16) h16 Ws[128*40];

    f32x4 acc[4][2];
    #pragma unroll
    for (int m = 0; m < 4; ++m)
        #pragma unroll
        for (int n = 0; n < 2; ++n)
            #pragma unroll
            for (int r = 0; r < 4; ++r) acc[m][n][r] = 0.f;

    for (int cs = 0; cs < 16; ++cs) {
        const int c0 = cs << 5;
        for (int id = tid; id < 64*4; id += 256) {
            const int row = id >> 2, g = id & 3;
            int t = t0c + tt*64 + row; if (t >= T_LEN) t = T_LEN - 1;
            *(f16x8*)(Xs + row*40 + g*8) = *(const f16x8*)(Xt + ((size_t)b*T_LEN + t)*CCH + c0 + g*8);
        }
        for (int id = tid; id < 128*4; id += 256) {
            const int row = id >> 2, g = id & 3;
            *(f16x8*)(Ws + row*40 + g*8) = *(const f16x8*)(Wd + (size_t)(r0 + row)*CCH + c0 + g*8);
        }
        __syncthreads();

        const f16x8 b0 = *(const f16x8*)(Ws + (w*32 +      lr)*40 + lg*8);
        const f16x8 b1 = *(const f16x8*)(Ws + (w*32 + 16 + lr)*40 + lg*8);
        #pragma unroll
        for (int m = 0; m < 4; ++m) {
            const f16x8 a = *(const f16x8*)(Xs + (m*16 + lr)*40 + lg*8);
            acc[m][0] = __builtin_amdgcn_mfma_f32_16x16x32_f16(a, b0, acc[m][0], 0, 0, 0);
            acc[m][1] = __builtin_amdgcn_mfma_f32_16x16x32_f16(a, b1, acc[m][1], 0, 0, 0);
        }
        __syncthreads();
    }

    #pragma unroll
    for (int nf = 0; nf < 2; ++nf) {
        const int row = r0 + w*32 + nf*16 + lr;
        const float bias = bi[row] + bh[row];
        #pragma unroll
        for (int m = 0; m < 4; ++m) {
            #pragma unroll
            for (int r = 0; r < 4; ++r) {
                const int tl = tt*64 + m*16 + lg*4 + r;
                if (tl < TC)
                    G[(((size_t)dir*TC + tl)*NBATCH + b)*GDIM + row]
                        = (h16)fixup(clamp_s(acc[m][nf][r] + bias, -60000.f, 60000.f), 0.f);
            }
        }
    }
}

// ---------------- persistent biLSTM recurrence, wave-k-split + readlane broadcast ----------------
// r12: waves_per_eu(1,4) -- min=1 lifts the VGPR resource cap so wreg[100] can live in registers.
//      out[] store deferred one step (prev_h/prev_t) so its vmcnt drain hides under the next dot phase.
__global__ __attribute__((amdgpu_flat_work_group_size(1024, 1024), amdgpu_waves_per_eu(1, 4)))
void lstm_chunk_kernel(const h16* __restrict__ G,
                       const unsigned* __restrict__ W16,
                       float* __restrict__ state,
                       float* __restrict__ out,
                       int t0f, int t0b, int first)
{
    const int tid  = threadIdx.x;
    const int lane = tid & 63;
    const int half = (tid >> 6) & 1;
    const int q    = tid >> 7;
    const int dir  = blockIdx.x >> 5;
    const int b    = blockIdx.x & 31;
    const int t0   = dir ? t0b : t0f;
    float* st = state + ((size_t)(dir*NBATCH + b))*2*HDIM;
    const unsigned* Wreg  = W16 + (size_t)dir*WREG_N*1024;
    const uint4*    Wlds4 = (const uint4*)(W16 + 204800 + (size_t)dir*28672);

    __shared__ __align__(16) uint4 lw4[WLDS_S*1024];   // 114,688 B
    __shared__ __align__(16) unsigned hs[HDIM/2];      // h as 128 f16-pairs
    __shared__ float pbuf[2*GDIM];                     // [half][row] partial sums, 8 KB

    unsigned wreg[WREG_N];
    #pragma unroll
    for (int p = 0; p < WREG_N; ++p)
        wreg[p] = Wreg[p*1024 + tid];                  // lane-coalesced

    #pragma unroll
    for (int s = 0; s < WLDS_S; ++s)
        lw4[s*1024 + tid] = Wlds4[s*1024 + tid];       // coalesced 16B/thread

    float hst = 0.0f, cst = 0.0f;
    if (tid < HDIM && !first) { hst = st[tid]; cst = st[HDIM + tid]; }
    if (tid < HDIM/2) {
        const float h0 = first ? 0.0f : st[2*tid];
        const float h1 = first ? 0.0f : st[2*tid + 1];
        hs[tid] = packh2(h0, h1);
    }
    __syncthreads();

    float2* pbuf2 = (float2*)pbuf;
    float prev_h = 0.0f;
    int   prev_t = -1;

    for (int i = 0; i < TC; ++i) {
        const int sl = dir ? (TC - 1 - i) : i;
        const int t  = t0 + sl;
        const h16* gp = G + (((size_t)dir*TC + sl)*NBATCH + b)*GDIM;
        float g0 = 0.f, g1 = 0.f, g2 = 0.f, g3 = 0.f;
        if (tid < HDIM) {
            // deferred store of previous step's h: vmcnt drain now hides under this step's dot phase
            if (prev_t >= 0)
                out[((size_t)b*T_LEN + prev_t)*(2*HDIM) + dir*HDIM + tid] = prev_h;
            g0 = (float)gp[tid];
            g1 = (float)gp[HDIM + tid];
            g2 = (float)gp[2*HDIM + tid];
            g3 = (float)gp[3*HDIM + tid];
        }

        const unsigned wv = hs[(half << 6) | lane];     // 1 ds_read_b32: lane l holds pair (half*64+l)

        float aA0 = 0.f, aA1 = 0.f, aB0 = 0.f, aB1 = 0.f;
        uint4 lwv;
        #pragma unroll
        for (int j = 0; j < 64; ++j) {
            const unsigned s = (unsigned)__builtin_amdgcn_readlane((int)wv, j);  // broadcast
            if ((j & 1) == 0) aA0 = dot2(s, wreg[j], aA0);
            else              aA1 = dot2(s, wreg[j], aA1);
            if (j < 36) {
                if ((j & 1) == 0) aB0 = dot2(s, wreg[64 + j], aB0);
                else              aB1 = dot2(s, wreg[64 + j], aB1);
            } else {
                const int jj = j - 36;
                if ((jj & 3) == 0) lwv = lw4[(jj >> 2)*1024 + tid];              // ds_read_b128
                const unsigned wp = ((const unsigned*)&lwv)[jj & 3];             // const idx after unroll
                if ((j & 1) == 0) aB0 = dot2(s, wp, aB0);
                else              aB1 = dot2(s, wp, aB1);
            }
        }
        // partials for rows rA=q*128+2l (x) and rB=rA+1 (y)
        pbuf2[(half << 9) | (q << 6) | lane] = make_float2(aA0 + aA1, aB0 + aB1);
        __syncthreads();

        if (tid < HDIM) {
            const float gi = g0 + pbuf[tid]            + pbuf[GDIM + tid];
            const float gf = g1 + pbuf[HDIM + tid]     + pbuf[GDIM + HDIM + tid];
            const float gg = g2 + pbuf[2*HDIM + tid]   + pbuf[GDIM + 2*HDIM + tid];
            const float go = g3 + pbuf[3*HDIM + tid]   + pbuf[GDIM + 3*HDIM + tid];
            const float c2 = sigm(gf)*cst + sigm(gi)*tanh_safe(gg);
            const float h2 = sigm(go)*tanh_safe(c2);
            hst = 0.1f*hst + 0.9f*h2;                   // zoneout (output is post-zoneout h)
            cst = 0.1f*cst + 0.9f*c2;
            prev_h = fixup(hst, 50.0f);
            prev_t = t;
            const float hn = __shfl_xor(hst, 1);
            if ((tid & 1) == 0) hs[tid >> 1] = packh2(hst, hn);
        }
        __syncthreads();
    }

    if (tid < HDIM) {
        if (prev_t >= 0)
            out[((size_t)b*T_LEN + prev_t)*(2*HDIM) + dir*HDIM + tid] = prev_h;
        st[tid] = hst; st[HDIM + tid] = cst;
    }
}

extern "C" void kernel_launch(void* const* d_in, const int* in_sizes, int n_in,
                              void* d_out, int out_size, void* d_ws, size_t ws_size,
                              hipStream_t stream)
{
    (void)in_sizes; (void)n_in; (void)out_size;
    if (ws_size < 49152000) return;

    const float* x     = (const float*)d_in[0];
    const float* cw0   = (const float*)d_in[1];
    const float* cb0   = (const float*)d_in[2];
    const float* bg0   = (const float*)d_in[3];
    const float* bb0   = (const float*)d_in[4];
    const float* bm0   = (const float*)d_in[5];
    const float* bv0   = (const float*)d_in[6];
    const float* cw1   = (const float*)d_in[7];
    const float* cb1   = (const float*)d_in[8];
    const float* bg1   = (const float*)d_in[9];
    const float* bb1   = (const float*)d_in[10];
    const float* bm1   = (const float*)d_in[11];
    const float* bv1   = (const float*)d_in[12];
    const float* cw2   = (const float*)d_in[13];
    const float* cb2   = (const float*)d_in[14];
    const float* bg2   = (const float*)d_in[15];
    const float* bb2   = (const float*)d_in[16];
    const float* bm2   = (const float*)d_in[17];
    const float* bv2   = (const float*)d_in[18];
    const float* wih_f = (const float*)d_in[19];
    const float* whh_f = (const float*)d_in[20];
    const float* bih_f = (const float*)d_in[21];
    const float* bhh_f = (const float*)d_in[22];
    const float* wih_b = (const float*)d_in[23];
    const float* whh_b = (const float*)d_in[24];
    const float* bih_b = (const float*)d_in[25];
    const float* bhh_b = (const float*)d_in[26];

    char* ws = (char*)d_ws;
    char* od = (char*)d_out;
    h16*      A   = (h16*)(ws);
    h16*      G   = (h16*)(ws + 32768000);
    float*    st  = (float*)(ws + 45875200);
    unsigned* W16 = (unsigned*)(ws + 46006272);
    h16*      Wg  = (h16*)(ws + 47054848);
    h16*      Bd  = (h16*)(od);
    h16*      Wp0 = (h16*)(od + 36000000);
    h16*      Wp1 = (h16*)(od + 36409600);
    h16*      Wp2 = (h16*)(od + 41652480);
    h16*      Xt0 = (h16*)(od + 46895360);
    float*    out = (float*)d_out;

    // packs
    pack_convw_kernel<<<dim3((5*512*80  + 255)/256), 256, 0, stream>>>(cw0, Wp0, 80);
    pack_convw_kernel<<<dim3((5*512*512 + 255)/256), 256, 0, stream>>>(cw1, Wp1, 512);
    pack_convw_kernel<<<dim3((5*512*512 + 255)/256), 256, 0, stream>>>(cw2, Wp2, 512);
    pack_wih_kernel<<<dim3(2*1024*512/256), 256, 0, stream>>>(wih_f, wih_b, Wg);
    whh_prep_kernel<<<dim3(1024), 256, 0, stream>>>(whh_f, whh_b, W16);
    x0_transpose_kernel<<<dim3(4, 32), 256, 0, stream>>>(x, Xt0);

    // convs (implicit-GEMM MFMA)
    const dim3 cgrid(8, 4, 32);
    conv_mfma_kernel<<<cgrid, 512, 0, stream>>>(Xt0, Wp0, A,  cb0, bg0, bb0, bm0, bv0, 80);
    conv_mfma_kernel<<<cgrid, 512, 0, stream>>>(A,   Wp1, Bd, cb1, bg1, bb1, bm1, bv1, 512);
    conv_mfma_kernel<<<cgrid, 512, 0, stream>>>(Bd,  Wp2, A,  cb2, bg2, bb2, bm2, bv2, 512);

    for (int c = 0; c < T_LEN / TC; ++c) {
        const int t0f = c * TC;
        const int t0b = (T_LEN - TC) - c * TC;
        gates_mfma_kernel<<<dim3(2, 8, 64), 256, 0, stream>>>(A, Wg, bih_f, bhh_f, bih_b, bhh_b, G, t0f, t0b);
        lstm_chunk_kernel<<<dim3(64), 1024, 0, stream>>>(G, W16, st, out, t0f, t0b, c == 0);
    }
}

// Round 14
// 2564.917 us; speedup vs baseline: 1.0956x; 1.0854x over previous
//
#include <hip/hip_runtime.h>

// Encoder: 3x [conv1d(K=5,pad2)+BN+ReLU] -> biLSTM(H=256) zoneout(0.1).  MFMA convs/gates; VALU recurrence.
// r13 lstm: NO weight registers (r5-r12's wreg[] was always scratch-spilled at the 64-VGPR cap).
//   Weights streamed per step: 23 uint4/thread from L2 (depth-3 rotating prefetch, coalesced chunk-major
//   layout) + 9 uint4/thread from persistent LDS (144 KB). Live set ~50 VGPR -- fits the cap by design.
// ws:    A f16 [32][1000][512] @0 (32,768,000) | G f16 [2][100][32][1024] @32,768,000 (13,107,200)
//        | state @45,875,200 (131,072) | W16 @46,006,272 (1,048,576) | Wg f16 [2][1024][512] @47,054,848 (2,097,152)
//        -> 49,152,000 B
// d_out: Bd (conv1 out) @0 | Wp0 @36,000,000 | Wp1 @36,409,600 | Wp2 @41,652,480 | Xt0 @46,895,360

#define T_LEN 1000
#define NBATCH 32
#define CCH 512
#define HDIM 256
#define GDIM 1024
#define TC 100

typedef _Float16 h16;
typedef _Float16 h16x2 __attribute__((ext_vector_type(2)));
typedef _Float16 f16x8 __attribute__((ext_vector_type(8)));
typedef float    f32x4 __attribute__((ext_vector_type(4)));

__device__ __forceinline__ float fixup(float v, float alt){
    union { float f; unsigned u; } c; c.f = v;
    return ((c.u & 0x7f800000u) == 0x7f800000u) ? alt : v;
}
__device__ __forceinline__ float clamp_s(float v, float lo, float hi){
    return fminf(fmaxf(v, lo), hi);
}
__device__ __forceinline__ float sigm(float x){
    const float xc = clamp_s(x, -30.f, 30.f);
    return 1.0f / (1.0f + __expf(-xc));
}
__device__ __forceinline__ float tanh_safe(float x){
    const float ax = fminf(fabsf(x), 30.0f);
    const float t  = __expf(-2.0f * ax);
    const float r  = (1.0f - t) / (1.0f + t);
    return copysignf(r, x);
}
__device__ __forceinline__ float mac2(unsigned hp, unsigned wp, float acc){
    union Cv { unsigned u; h16 h[2]; };
    Cv a, b; a.u = hp; b.u = wp;
    acc += (float)a.h[0] * (float)b.h[0];
    acc += (float)a.h[1] * (float)b.h[1];
    return acc;
}
__device__ __forceinline__ float dot2(unsigned hp, unsigned wp, float acc){
#if defined(__has_builtin) && __has_builtin(__builtin_amdgcn_fdot2)
    union Cv { unsigned u; h16x2 v; };
    Cv a, b; a.u = hp; b.u = wp;
    return __builtin_amdgcn_fdot2(a.v, b.v, acc, false);
#else
    return mac2(hp, wp, acc);
#endif
}
__device__ __forceinline__ unsigned packh2(float x, float y){
    union Cv { unsigned u; h16 h[2]; };
    Cv c; c.h[0] = (h16)x; c.h[1] = (h16)y;
    return c.u;
}

// ---------------- packs ----------------
// cw f32 [512][cin][5] -> Wp f16 [5][512][cin]
__global__ __launch_bounds__(256)
void pack_convw_kernel(const float* __restrict__ cw, h16* __restrict__ Wp, int cin)
{
    const int n = blockIdx.x*256 + threadIdx.x;
    if (n >= 5*512*cin) return;
    const int k   = n / (512*cin);
    const int rem = n - k*512*cin;
    const int co  = rem / cin;
    const int ci  = rem - co*cin;
    Wp[n] = (h16)cw[((size_t)co*cin + ci)*5 + k];
}

// wih f32 [1024][512] x2 -> Wg f16 [2][1024][512]
__global__ __launch_bounds__(256)
void pack_wih_kernel(const float* __restrict__ wf, const float* __restrict__ wb, h16* __restrict__ Wg)
{
    const int n = blockIdx.x*256 + threadIdx.x;
    const float* src = (n < 1024*512) ? wf : wb;
    Wg[n] = (h16)src[n & (1024*512 - 1)];
}

// whh f32 -> chunk-major stream pack for r13 lstm.
// Thread t: half=(t>>6)&1, q=t>>7, l=t&63; rows rA=q*128+2l, rB=rA+1; k-pairs P in [64*half, 64*half+64).
// Layout (u32 addr = dir*131072 + chunk*4096 + t*4 + e), chunk 0..31:
//   chunk 0..6   (global stream, rowA tail) : row=rA, P=64*half+4*(9+chunk)+e
//   chunk 7..22  (global stream, rowB)      : row=rB, P=64*half+4*(chunk-7)+e
//   chunk 23..31 (LDS slab,     rowA head)  : row=rA, P=64*half+4*(chunk-23)+e
__global__ __launch_bounds__(256)
void whh_prep_kernel(const float* __restrict__ whh_f, const float* __restrict__ whh_b,
                     unsigned* __restrict__ W16)
{
    const int n = blockIdx.x * 256 + threadIdx.x;   // 262144
    if (n >= 2*128*1024) return;
    const int dir   = n >> 17;
    const int rem   = n & 131071;
    const int chunk = rem >> 12;
    const int idx   = rem & 4095;
    const int t     = idx >> 2;
    const int e     = idx & 3;
    const float* whh = dir ? whh_b : whh_f;
    const int half = (t >> 6) & 1;
    const int q    = t >> 7;
    const int l    = t & 63;
    const int rA   = q*128 + 2*l;
    int row, P;
    if (chunk < 7)       { row = rA;     P = 64*half + 4*(9 + chunk) + e; }
    else if (chunk < 23) { row = rA + 1; P = 64*half + 4*(chunk - 7) + e; }
    else                 { row = rA;     P = 64*half + 4*(chunk - 23) + e; }
    W16[n] = packh2(whh[(size_t)row*HDIM + 2*P], whh[(size_t)row*HDIM + 2*P + 1]);
}

// x f32 [32][80][1000] -> Xt0 f16 [32][1000][80]
__global__ __launch_bounds__(256)
void x0_transpose_kernel(const float* __restrict__ x, h16* __restrict__ Xt0)
{
    const int b = blockIdx.y;
    const int t = blockIdx.x*256 + threadIdx.x;
    if (t >= T_LEN) return;
    h16 v[80];
    #pragma unroll
    for (int c = 0; c < 80; ++c) v[c] = (h16)x[((size_t)b*80 + c)*T_LEN + t];
    #pragma unroll
    for (int g = 0; g < 10; ++g)
        *(f16x8*)(Xt0 + ((size_t)b*T_LEN + t)*80 + g*8) = *(const f16x8*)(v + g*8);
}

// ---------------- conv (implicit GEMM, MFMA 16x16x32 f16) ----------------
__global__ __attribute__((amdgpu_flat_work_group_size(512,512), amdgpu_waves_per_eu(4,4)))
void conv_mfma_kernel(const h16* __restrict__ Xt, const h16* __restrict__ Wp,
                      h16* __restrict__ outp,
                      const float* __restrict__ cb, const float* __restrict__ bg,
                      const float* __restrict__ bb, const float* __restrict__ bm,
                      const float* __restrict__ bv, int cin)
{
    const int t0   = blockIdx.x * 128;
    const int co0  = blockIdx.y * 128;
    const int b    = blockIdx.z;
    const int tid  = threadIdx.x;
    const int lane = tid & 63;
    const int w    = tid >> 6;
    const int wm   = w >> 2;
    const int wn   = w & 3;
    const int lr   = lane & 15;
    const int lg   = lane >> 4;

    __shared__ __align__(16) h16 Xs[132*40];
    __shared__ __align__(16) h16 Ws[5*128*40];

    f32x4 acc[4][2];
    #pragma unroll
    for (int m = 0; m < 4; ++m)
        #pragma unroll
        for (int n = 0; n < 2; ++n)
            #pragma unroll
            for (int r = 0; r < 4; ++r) acc[m][n][r] = 0.f;

    const int ksteps = (cin + 31) >> 5;
    for (int cs = 0; cs < ksteps; ++cs) {
        const int c0 = cs << 5;
        for (int id = tid; id < 132*4; id += 512) {
            const int row = id >> 2, g = id & 3;
            const int t = t0 + row - 2;
            f16x8 v;
            #pragma unroll
            for (int j = 0; j < 8; ++j) v[j] = (h16)0.f;
            if (t >= 0 && t < T_LEN) {
                const int c = c0 + g*8;
                if (c + 8 <= cin) {
                    v = *(const f16x8*)(Xt + ((size_t)b*T_LEN + t)*cin + c);
                } else if (c < cin) {
                    #pragma unroll
                    for (int j = 0; j < 8; ++j) if (c + j < cin) v[j] = Xt[((size_t)b*T_LEN + t)*cin + c + j];
                }
            }
            *(f16x8*)(Xs + row*40 + g*8) = v;
        }
        for (int id = tid; id < 5*128*4; id += 512) {
            const int k  = id >> 9;
            const int co = (id >> 2) & 127;
            const int g  = id & 3;
            const int c  = c0 + g*8;
            f16x8 v;
            #pragma unroll
            for (int j = 0; j < 8; ++j) v[j] = (h16)0.f;
            if (c + 8 <= cin) {
                v = *(const f16x8*)(Wp + ((size_t)k*512 + co0 + co)*cin + c);
            } else if (c < cin) {
                #pragma unroll
                for (int j = 0; j < 8; ++j) if (c + j < cin) v[j] = Wp[((size_t)k*512 + co0 + co)*cin + c + j];
            }
            *(f16x8*)(Ws + (k*128 + co)*40 + g*8) = v;
        }
        __syncthreads();

        #pragma unroll
        for (int k = 0; k < 5; ++k) {
            const f16x8 b0 = *(const f16x8*)(Ws + (k*128 + wn*32 +      lr)*40 + lg*8);
            const f16x8 b1 = *(const f16x8*)(Ws + (k*128 + wn*32 + 16 + lr)*40 + lg*8);
            #pragma unroll
            for (int m = 0; m < 4; ++m) {
                const f16x8 a = *(const f16x8*)(Xs + (wm*64 + m*16 + lr + k)*40 + lg*8);
                acc[m][0] = __builtin_amdgcn_mfma_f32_16x16x32_f16(a, b0, acc[m][0], 0, 0, 0);
                acc[m][1] = __builtin_amdgcn_mfma_f32_16x16x32_f16(a, b1, acc[m][1], 0, 0, 0);
            }
        }
        __syncthreads();
    }

    #pragma unroll
    for (int nf = 0; nf < 2; ++nf) {
        const int co = co0 + wn*32 + nf*16 + lr;
        const float s  = bg[co] * rsqrtf(fmaxf(bv[co] + 1e-5f, 1e-8f));
        const float sh = (cb[co] - bm[co]) * s + bb[co];
        #pragma unroll
        for (int m = 0; m < 4; ++m) {
            #pragma unroll
            for (int r = 0; r < 4; ++r) {
                const int t = t0 + wm*64 + m*16 + lg*4 + r;
                if (t < T_LEN) {
                    const float y = fixup(clamp_s(fmaxf(acc[m][nf][r]*s + sh, 0.f), 0.f, 60000.f), 0.f);
                    outp[((size_t)b*T_LEN + t)*CCH + co] = (h16)y;
                }
            }
        }
    }
}

// ---------------- gates GEMM (MFMA), one time-chunk, both dirs ----------------
__global__ __attribute__((amdgpu_flat_work_group_size(256,256), amdgpu_waves_per_eu(4,4)))
void gates_mfma_kernel(const h16* __restrict__ Xt,
                       const h16* __restrict__ Wg,
                       const float* __restrict__ bih_f, const float* __restrict__ bhh_f,
                       const float* __restrict__ bih_b, const float* __restrict__ bhh_b,
                       h16* __restrict__ G, int t0f, int t0b)
{
    const int tt   = blockIdx.x;
    const int r0   = blockIdx.y * 128;
    const int b    = blockIdx.z & 31;
    const int dir  = blockIdx.z >> 5;
    const int t0c  = dir ? t0b : t0f;
    const int tid  = threadIdx.x;
    const int lane = tid & 63;
    const int w    = tid >> 6;
    const int lr   = lane & 15;
    const int lg   = lane >> 4;
    const float* bi = dir ? bih_b : bih_f;
    const float* bh = dir ? bhh_b : bhh_f;
    const h16* Wd = Wg + (size_t)dir*1024*512;

    __shared__ __align__(16) h16 Xs[64*40];
    __shared__ __align__(16) h16 Ws[128*40];

    f32x4 acc[4][2];
    #pragma unroll
    for (int m = 0; m < 4; ++m)
        #pragma unroll
        for (int n = 0; n < 2; ++n)
            #pragma unroll
            for (int r = 0; r < 4; ++r) acc[m][n][r] = 0.f;

    for (int cs = 0; cs < 16; ++cs) {
        const int c0 = cs << 5;
        for (int id = tid; id < 64*4; id += 256) {
            const int row = id >> 2, g = id & 3;
            int t = t0c + tt*64 + row; if (t >= T_LEN) t = T_LEN - 1;
            *(f16x8*)(Xs + row*40 + g*8) = *(const f16x8*)(Xt + ((size_t)b*T_LEN + t)*CCH + c0 + g*8);
        }
        for (int id = tid; id < 128*4; id += 256) {
            const int row = id >> 2, g = id & 3;
            *(f16x8*)(Ws + row*40 + g*8) = *(const f16x8*)(Wd + (size_t)(r0 + row)*CCH + c0 + g*8);
        }
        __syncthreads();

        const f16x8 b0 = *(const f16x8*)(Ws + (w*32 +      lr)*40 + lg*8);
        const f16x8 b1 = *(const f16x8*)(Ws + (w*32 + 16 + lr)*40 + lg*8);
        #pragma unroll
        for (int m = 0; m < 4; ++m) {
            const f16x8 a = *(const f16x8*)(Xs + (m*16 + lr)*40 + lg*8);
            acc[m][0] = __builtin_amdgcn_mfma_f32_16x16x32_f16(a, b0, acc[m][0], 0, 0, 0);
            acc[m][1] = __builtin_amdgcn_mfma_f32_16x16x32_f16(a, b1, acc[m][1], 0, 0, 0);
        }
        __syncthreads();
    }

    #pragma unroll
    for (int nf = 0; nf < 2; ++nf) {
        const int row = r0 + w*32 + nf*16 + lr;
        const float bias = bi[row] + bh[row];
        #pragma unroll
        for (int m = 0; m < 4; ++m) {
            #pragma unroll
            for (int r = 0; r < 4; ++r) {
                const int tl = tt*64 + m*16 + lg*4 + r;
                if (tl < TC)
                    G[(((size_t)dir*TC + tl)*NBATCH + b)*GDIM + row]
                        = (h16)fixup(clamp_s(acc[m][nf][r] + bias, -60000.f, 60000.f), 0.f);
            }
        }
    }
}

// ---------------- persistent biLSTM recurrence: L2 weight streaming, no weight registers ----------------
// Thread t: half=(t>>6)&1 (wave parity = k-half), q=t>>7, l=t&63; rows rA=q*128+2l, rB=rA+1.
// Per step: readlane h-broadcast (r10); rowA chunks 0..8 from persistent LDS, rowA 9..15 + rowB 0..15
// streamed from L2 as uint4 with depth-3 rotating prefetch (pipelined, unlike compiler spill reloads).
__global__ __attribute__((amdgpu_flat_work_group_size(1024, 1024), amdgpu_waves_per_eu(4, 4)))
void lstm_chunk_kernel(const h16* __restrict__ G,
                       const unsigned* __restrict__ W16,
                       float* __restrict__ state,
                       float* __restrict__ out,
                       int t0f, int t0b, int first)
{
    const int tid  = threadIdx.x;
    const int lane = tid & 63;
    const int half = (tid >> 6) & 1;
    const int q    = tid >> 7;
    const int dir  = blockIdx.x >> 5;
    const int b    = blockIdx.x & 31;
    const int t0   = dir ? t0b : t0f;
    float* st = state + ((size_t)(dir*NBATCH + b))*2*HDIM;
    const uint4* Wg4 = (const uint4*)W16 + (size_t)dir*32768;   // 32 chunks x 1024 uint4
    const uint4* Wl4 = Wg4 + 23*1024;                            // LDS-slab source (chunks 23..31)

    __shared__ __align__(16) uint4 lw4[9*1024];        // 144 KB: rowA chunks 0..8
    __shared__ __align__(16) unsigned hs[HDIM/2];      // h as 128 f16-pairs
    __shared__ float pbuf[2*GDIM];                     // [half][row] partials, 8 KB

    #pragma unroll
    for (int s = 0; s < 9; ++s)
        lw4[s*1024 + tid] = Wl4[s*1024 + tid];         // coalesced 16B/thread

    float hst = 0.0f, cst = 0.0f;
    if (tid < HDIM && !first) { hst = st[tid]; cst = st[HDIM + tid]; }
    if (tid < HDIM/2) {
        const float h0 = first ? 0.0f : st[2*tid];
        const float h1 = first ? 0.0f : st[2*tid + 1];
        hs[tid] = packh2(h0, h1);
    }
    __syncthreads();

    float2* pbuf2 = (float2*)pbuf;
    float prev_h = 0.0f;
    int   prev_t = -1;

    for (int i = 0; i < TC; ++i) {
        const int sl = dir ? (TC - 1 - i) : i;
        const int t  = t0 + sl;
        const h16* gp = G + (((size_t)dir*TC + sl)*NBATCH + b)*GDIM;

        const unsigned wv = hs[(half << 6) | lane];     // 1 ds_read_b32; lane j holds h-pair 64*half+j

        // prologue prefetch: rowB depth-3, LDS rowA depth-2
        uint4 b0 = Wg4[7*1024 + tid];
        uint4 b1 = Wg4[8*1024 + tid];
        uint4 b2 = Wg4[9*1024 + tid];
        uint4 l0 = lw4[tid];
        uint4 l1 = lw4[1024 + tid];
        uint4 a0{}, a1{}, a2{};

        float g0 = 0.f, g1 = 0.f, g2 = 0.f, g3 = 0.f;
        if (tid < HDIM) {
            if (prev_t >= 0)                            // deferred store: drain hides under dots
                out[((size_t)b*T_LEN + prev_t)*(2*HDIM) + dir*HDIM + tid] = prev_h;
            g0 = (float)gp[tid];
            g1 = (float)gp[HDIM + tid];
            g2 = (float)gp[2*HDIM + tid];
            g3 = (float)gp[3*HDIM + tid];
        }

        float aA0 = 0.f, aA1 = 0.f, aB0 = 0.f, aB1 = 0.f;
        #pragma unroll
        for (int c = 0; c < 16; ++c) {
            const uint4 wa = (c < 9) ? l0 : a0;         // rowA source
            const uint4 wb = b0;                        // rowB source
            // rotate + issue next loads (independent of the dots below; scheduler hoists)
            b0 = b1; b1 = b2;
            if (c + 3 < 16) b2 = Wg4[(7 + c + 3)*1024 + tid];
            if (c < 9) { l0 = l1; if (c + 2 < 9) l1 = lw4[(c + 2)*1024 + tid]; }
            else       { a0 = a1; a1 = a2; }
            if (c >= 6 && c < 13) {                     // load rowA-tail chunk (c-6), used at c+3
                const uint4 av = Wg4[(c - 6)*1024 + tid];
                if      (c == 6) a0 = av;
                else if (c == 7) a1 = av;
                else             a2 = av;
            }
            // consume: h pairs j = 4c..4c+3
            const unsigned s0 = (unsigned)__builtin_amdgcn_readlane((int)wv, 4*c + 0);
            const unsigned s1 = (unsigned)__builtin_amdgcn_readlane((int)wv, 4*c + 1);
            const unsigned s2 = (unsigned)__builtin_amdgcn_readlane((int)wv, 4*c + 2);
            const unsigned s3 = (unsigned)__builtin_amdgcn_readlane((int)wv, 4*c + 3);
            aA0 = dot2(s0, wa.x, aA0);  aA1 = dot2(s1, wa.y, aA1);
            aA0 = dot2(s2, wa.z, aA0);  aA1 = dot2(s3, wa.w, aA1);
            aB0 = dot2(s0, wb.x, aB0);  aB1 = dot2(s1, wb.y, aB1);
            aB0 = dot2(s2, wb.z, aB0);  aB1 = dot2(s3, wb.w, aB1);
        }
        // partials for rows rA=q*128+2l (x) and rB=rA+1 (y)
        pbuf2[(half << 9) | (q << 6) | lane] = make_float2(aA0 + aA1, aB0 + aB1);
        __syncthreads();

        if (tid < HDIM) {
            const float gi = g0 + pbuf[tid]            + pbuf[GDIM + tid];
            const float gf = g1 + pbuf[HDIM + tid]     + pbuf[GDIM + HDIM + tid];
            const float gg = g2 + pbuf[2*HDIM + tid]   + pbuf[GDIM + 2*HDIM + tid];
            const float go = g3 + pbuf[3*HDIM + tid]   + pbuf[GDIM + 3*HDIM + tid];
            const float c2 = sigm(gf)*cst + sigm(gi)*tanh_safe(gg);
            const float h2 = sigm(go)*tanh_safe(c2);
            hst = 0.1f*hst + 0.9f*h2;                   // zoneout (output is post-zoneout h)
            cst = 0.1f*cst + 0.9f*c2;
            prev_h = fixup(hst, 50.0f);
            prev_t = t;
            const float hn = __shfl_xor(hst, 1);
            if ((tid & 1) == 0) hs[tid >> 1] = packh2(hst, hn);
        }
        __syncthreads();
    }

    if (tid < HDIM) {
        if (prev_t >= 0)
            out[((size_t)b*T_LEN + prev_t)*(2*HDIM) + dir*HDIM + tid] = prev_h;
        st[tid] = hst; st[HDIM + tid] = cst;
    }
}

extern "C" void kernel_launch(void* const* d_in, const int* in_sizes, int n_in,
                              void* d_out, int out_size, void* d_ws, size_t ws_size,
                              hipStream_t stream)
{
    (void)in_sizes; (void)n_in; (void)out_size;
    if (ws_size < 49152000) return;

    const float* x     = (const float*)d_in[0];
    const float* cw0   = (const float*)d_in[1];
    const float* cb0   = (const float*)d_in[2];
    const float* bg0   = (const float*)d_in[3];
    const float* bb0   = (const float*)d_in[4];
    const float* bm0   = (const float*)d_in[5];
    const float* bv0   = (const float*)d_in[6];
    const float* cw1   = (const float*)d_in[7];
    const float* cb1   = (const float*)d_in[8];
    const float* bg1   = (const float*)d_in[9];
    const float* bb1   = (const float*)d_in[10];
    const float* bm1   = (const float*)d_in[11];
    const float* bv1   = (const float*)d_in[12];
    const float* cw2   = (const float*)d_in[13];
    const float* cb2   = (const float*)d_in[14];
    const float* bg2   = (const float*)d_in[15];
    const float* bb2   = (const float*)d_in[16];
    const float* bm2   = (const float*)d_in[17];
    const float* bv2   = (const float*)d_in[18];
    const float* wih_f = (const float*)d_in[19];
    const float* whh_f = (const float*)d_in[20];
    const float* bih_f = (const float*)d_in[21];
    const float* bhh_f = (const float*)d_in[22];
    const float* wih_b = (const float*)d_in[23];
    const float* whh_b = (const float*)d_in[24];
    const float* bih_b = (const float*)d_in[25];
    const float* bhh_b = (const float*)d_in[26];

    char* ws = (char*)d_ws;
    char* od = (char*)d_out;
    h16*      A   = (h16*)(ws);
    h16*      G   = (h16*)(ws + 32768000);
    float*    st  = (float*)(ws + 45875200);
    unsigned* W16 = (unsigned*)(ws + 46006272);
    h16*      Wg  = (h16*)(ws + 47054848);
    h16*      Bd  = (h16*)(od);
    h16*      Wp0 = (h16*)(od + 36000000);
    h16*      Wp1 = (h16*)(od + 36409600);
    h16*      Wp2 = (h16*)(od + 41652480);
    h16*      Xt0 = (h16*)(od + 46895360);
    float*    out = (float*)d_out;

    // packs
    pack_convw_kernel<<<dim3((5*512*80  + 255)/256), 256, 0, stream>>>(cw0, Wp0, 80);
    pack_convw_kernel<<<dim3((5*512*512 + 255)/256), 256, 0, stream>>>(cw1, Wp1, 512);
    pack_convw_kernel<<<dim3((5*512*512 + 255)/256), 256, 0, stream>>>(cw2, Wp2, 512);
    pack_wih_kernel<<<dim3(2*1024*512/256), 256, 0, stream>>>(wih_f, wih_b, Wg);
    whh_prep_kernel<<<dim3(1024), 256, 0, stream>>>(whh_f, whh_b, W16);
    x0_transpose_kernel<<<dim3(4, 32), 256, 0, stream>>>(x, Xt0);

    // convs (implicit-GEMM MFMA)
    const dim3 cgrid(8, 4, 32);
    conv_mfma_kernel<<<cgrid, 512, 0, stream>>>(Xt0, Wp0, A,  cb0, bg0, bb0, bm0, bv0, 80);
    conv_mfma_kernel<<<cgrid, 512, 0, stream>>>(A,   Wp1, Bd, cb1, bg1, bb1, bm1, bv1, 512);
    conv_mfma_kernel<<<cgrid, 512, 0, stream>>>(Bd,  Wp2, A,  cb2, bg2, bb2, bm2, bv2, 512);

    for (int c = 0; c < T_LEN / TC; ++c) {
        const int t0f = c * TC;
        const int t0b = (T_LEN - TC) - c * TC;
        gates_mfma_kernel<<<dim3(2, 8, 64), 256, 0, stream>>>(A, Wg, bih_f, bhh_f, bih_b, bhh_b, G, t0f, t0b);
        lstm_chunk_kernel<<<dim3(64), 1024, 0, stream>>>(G, W16, st, out, t0f, t0b, c == 0);
    }
}